// Round 12
// baseline (1102.934 us; speedup 1.0000x reference)
//
#include <hip/hip_runtime.h>
#include <hip/hip_bf16.h>

// Problem constants (fixed by setup_inputs)
#define BB_  64
#define TT_  512
#define FF_  1024
#define HH_  31
#define GG_  124   // 4*H
#define FUT_ 16
#define TTOT_ 528  // T + future
#define OUT_ROW_ ((size_t)TTOT_ * FF_)   // per-batch stride in output

// ---- workspace layout (float indices) ----
#define PRE1_OFF ((size_t)0)                              // [512][64][128]
#define H2A_OFF  (PRE1_OFF + (size_t)TT_*64*128)          // [528*64][32]
#define WT_OFF   (H2A_OFF  + (size_t)TTOT_*64*32)         // [31][1024]
#define MV_OFF   (WT_OFF   + 31*1024)                     // [124][32]
#define FLG_OFF  (MV_OFF   + 124*32)                      // flag ints

#define KBLK   64            // k2-role blocks (0..63, dispatched first -> own CUs)
#define NCONS  128           // consumer blocks (64..191)
#define NCHUNK (TTOT_ * 2)   // 1056 chunks of 32 h2a rows

__device__ __forceinline__ float rdlane(float v, int k) {
    return __uint_as_float(__builtin_amdgcn_readlane(__float_as_uint(v), k));
}
__device__ __forceinline__ int aload_acq(int* p) {
    return __hip_atomic_load(p, __ATOMIC_ACQUIRE, __HIP_MEMORY_SCOPE_AGENT);
}
__device__ __forceinline__ void aadd_rel(int* p, int v) {
    __hip_atomic_fetch_add(p, v, __ATOMIC_RELEASE, __HIP_MEMORY_SCOPE_AGENT);
}

// repeat macros
#define REP31(M) M(0) M(1) M(2) M(3) M(4) M(5) M(6) M(7) M(8) M(9) \
                 M(10) M(11) M(12) M(13) M(14) M(15) M(16) M(17) M(18) M(19) \
                 M(20) M(21) M(22) M(23) M(24) M(25) M(26) M(27) M(28) M(29) M(30)
#define REP16E(M) M(0) M(2) M(4) M(6) M(8) M(10) M(12) M(14) \
                  M(16) M(18) M(20) M(22) M(24) M(26) M(28) M(30)
#define REP15O(M) M(1) M(3) M(5) M(7) M(9) M(11) M(13) M(15) \
                  M(17) M(19) M(21) M(23) M(25) M(27) M(29)

// ---------------- K_ZERO: clear flag region ----------------
__global__ void k_zero(int* flg) {
    if (threadIdx.x < 16) flg[threadIdx.x] = 0;
}

// ---------------- K_FRONT: fused k1(v3 + swizzle) + k0 + k0b ----------------
// blocks 0..255: k1 role (2 timesteps x 128 gates, 8x8 register tile).
// STAGING SWIZZLE (new): the write pattern xs[row][r] with row-stride 128
// floats put 8 lanes in the same bank (8-way conflict, 2.2e7 counted in R11).
// Store element (row, col) at col ^ ((row>>2 & 7) * 8); reads apply the same
// XOR. 8-way -> 2-way (free). Pure layout change -> bit-identical pre1.
// blocks 256..379: k0 (WT transpose). blocks 380..395: k0b (Mv).
__global__ __launch_bounds__(256) void k_front(
    const float* __restrict__ X,
    const float* __restrict__ Wih1,
    const float* __restrict__ bih1,
    const float* __restrict__ bhh1,
    const float* __restrict__ Wlin,
    const float* __restrict__ blin,
    float* __restrict__ pre1,
    float* __restrict__ WT,
    float* __restrict__ Mv)
{
    __shared__ __align__(16) float xs[32][128];
    __shared__ __align__(16) float ws[32][128];
    const int blk = blockIdx.x;
    const int tid = threadIdx.x;

    if (blk < 256) {
        const int t0   = blk * 2;
        const int tcol = tid & 15, trow = tid >> 4;
        const int c0 = tcol * 8, r0 = trow * 8;

        float4 a0[8], a1[8];
#pragma unroll
        for (int r = 0; r < 8; r++) { a0[r] = make_float4(0.f,0.f,0.f,0.f); a1[r] = a0[r]; }

        for (int kc = 0; kc < 32; ++kc) {
            const int k0f = kc * 32;
#pragma unroll
            for (int p = 0; p < 4; p++) {
                int i = tid + p * 256;
                int r = i >> 3, f = i & 7;
                int bb = r & 63, tt = t0 + (r >> 6);
                float4 v = *(const float4*)(X + (size_t)bb * TT_ * FF_ + (size_t)tt * FF_ + k0f + f * 4);
                const int sc = r ^ (f << 3);      // swizzled col (rows f*4..f*4+3 share f)
                xs[f * 4 + 0][sc] = v.x; xs[f * 4 + 1][sc] = v.y;
                xs[f * 4 + 2][sc] = v.z; xs[f * 4 + 3][sc] = v.w;
            }
#pragma unroll
            for (int p = 0; p < 4; p++) {
                int i = tid + p * 256;
                int g = i >> 3, f = i & 7;
                float4 v = make_float4(0.f, 0.f, 0.f, 0.f);
                if (g < GG_) v = *(const float4*)(Wih1 + (size_t)g * FF_ + k0f + f * 4);
                const int sg = g ^ (f << 3);
                ws[f * 4 + 0][sg] = v.x; ws[f * 4 + 1][sg] = v.y;
                ws[f * 4 + 2][sg] = v.z; ws[f * 4 + 3][sg] = v.w;
            }
            __syncthreads();
#pragma unroll
            for (int k = 0; k < 32; k++) {
                const int xk = ((k >> 2) & 7) << 3;       // read-side XOR
                const int cb = c0 ^ xk;
                const int rb = r0 ^ xk;
                float4 wv0 = *(const float4*)&ws[k][cb];
                float4 wv1 = *(const float4*)&ws[k][cb + 4];
                float4 xa  = *(const float4*)&xs[k][rb];
                float4 xb  = *(const float4*)&xs[k][rb + 4];
                float rx[8] = {xa.x, xa.y, xa.z, xa.w, xb.x, xb.y, xb.z, xb.w};
#pragma unroll
                for (int r = 0; r < 8; r++) {
                    a0[r].x += rx[r] * wv0.x; a0[r].y += rx[r] * wv0.y;
                    a0[r].z += rx[r] * wv0.z; a0[r].w += rx[r] * wv0.w;
                    a1[r].x += rx[r] * wv1.x; a1[r].y += rx[r] * wv1.y;
                    a1[r].z += rx[r] * wv1.z; a1[r].w += rx[r] * wv1.w;
                }
            }
            __syncthreads();
        }
        float bias0[4], bias1[4];
#pragma unroll
        for (int cc = 0; cc < 4; cc++) {
            int c = c0 + cc;
            bias0[cc] = (c < GG_) ? (bih1[c] + bhh1[c]) : 0.0f;
            c = c0 + 4 + cc;
            bias1[cc] = (c < GG_) ? (bih1[c] + bhh1[c]) : 0.0f;
        }
#pragma unroll
        for (int r = 0; r < 8; r++) {
            int row = r0 + r;
            int m = (t0 + (row >> 6)) * 64 + (row & 63);
            float4 o0 = a0[r], o1 = a1[r];
            o0.x += bias0[0]; o0.y += bias0[1]; o0.z += bias0[2]; o0.w += bias0[3];
            o1.x += bias1[0]; o1.y += bias1[1]; o1.z += bias1[2]; o1.w += bias1[3];
            *(float4*)(pre1 + (size_t)m * 128 + c0)     = o0;
            *(float4*)(pre1 + (size_t)m * 128 + c0 + 4) = o1;
        }
    } else if (blk < 380) {
        int i = (blk - 256) * 256 + tid;   // 124*256 = 31744 = 1024*31
        int j = i / 31;
        int k = i - j * 31;
        WT[k * 1024 + j] = Wlin[i];
    } else {
        int idx = (blk - 380) * 256 + tid;
        if (idx < GG_ * 32) {
            int g = idx >> 5, k = idx & 31;
            const float* wr = Wih1 + (size_t)g * FF_;
            float acc = 0.0f;
            if (k < 31) {
#pragma unroll 8
                for (int j = 0; j < FF_; j++) acc += wr[j] * Wlin[j * 31 + k];
            } else {
#pragma unroll 8
                for (int j = 0; j < FF_; j++) acc += wr[j] * blin[j];
            }
            Mv[idx] = acc;
        }
    }
}

// ---------------- K_23: k2 (R6 body) overlapped with k3 consumers ----------------
// 192 blocks total (<=256 -> breadth-first dispatch gives ONE block per CU: no
// CU sharing, unlike R11's 576-block variant whose producers slowed k2 1.8x).
// blocks 0..63: k2 role (R6 body verbatim; 128 active threads + barrier-matched
// skeleton). Publishes progress per 64-step group: flg[g]+=1 (release) after
// h2a stores of t = 64g+63; flg[7] after tail (t=511); flg[8] after the future
// loop. blocks 64..191: k3 consumers, static chunk ownership (c = cid; c += 128),
// each chunk waits for its group flag ==64 (acquire). k2 never waits on
// consumers -> acyclic -> deadlock-free. Numeric bodies verbatim from R9 ->
// bit-identical output (absmax must stay 0.001953125).
__global__ __launch_bounds__(256) void k_23(
    const float* __restrict__ pre1,
    const float* __restrict__ Whh1,
    const float* __restrict__ Wih2,
    const float* __restrict__ Whh2,
    const float* __restrict__ bih1, const float* __restrict__ bhh1,
    const float* __restrict__ bih2, const float* __restrict__ bhh2,
    const float* __restrict__ Mv,
    const float* __restrict__ WT,
    const float* __restrict__ blin,
    float* __restrict__ h2a,
    float* __restrict__ out,
    int*   __restrict__ flg)
{
    __shared__ __align__(16) float smem[1024];   // k2: gA/g2 (512 fl); cons: hl (1024 fl)
    const int blk = blockIdx.x;
    const int tid = threadIdx.x;

    if (blk >= KBLK) {
        // ================= CONSUMER: k3 chunks as h2a groups complete =========
        float (*hl)[32] = (float(*)[32])smem;
        const int cid = blk - KBLK;          // 0..127
        int gseen = 0;
        for (int c = cid; c < NCHUNK; c += NCONS) {
            const int m0 = c * 32;
            const int t  = m0 >> 6;
            const int g  = (t < TT_) ? (t >> 6) : 8;
            while (gseen <= g) {
                if (aload_acq(&flg[gseen]) == KBLK) gseen++;
                else __builtin_amdgcn_s_sleep(8);
            }
#pragma unroll
            for (int p = 0; p < 4; p++) {
                int i = tid + p * 256;
                int r = i >> 5, k = i & 31;
                hl[r][k] = h2a[(size_t)(m0 + r) * 32 + k];
            }
            __syncthreads();
            const int c0 = tid * 4;
            float4 bl = *(const float4*)(blin + c0);
            float4 acc[32];
#pragma unroll
            for (int r = 0; r < 32; r++) acc[r] = bl;
            for (int k = 0; k < 31; k++) {
                float4 wv = *(const float4*)(WT + k * 1024 + c0);
#pragma unroll
                for (int r = 0; r < 32; r++) {
                    float h = hl[r][k];
                    acc[r].x += h * wv.x; acc[r].y += h * wv.y;
                    acc[r].z += h * wv.z; acc[r].w += h * wv.w;
                }
            }
            const int b0 = m0 & 63;
#pragma unroll
            for (int r = 0; r < 32; r++) {
                int b = b0 + r;
                *(float4*)(out + (size_t)b * OUT_ROW_ + (size_t)t * FF_ + c0) = acc[r];
            }
            __syncthreads();   // protect hl before next chunk
        }
        return;
    }

    // ===================== K2-ROLE BLOCK (blk 0..63) ==========================
    if (tid >= 128) {
        // barrier-count skeleton (1 + 511 + 1 + 32 = 545)
        __syncthreads();
        for (int t = 0; t < TT_ - 1; t++) __syncthreads();
        __syncthreads();
        for (int s = 0; s < FUT_; s++) { __syncthreads(); __syncthreads(); }
        return;
    }

    {
        const int L  = tid;               // 0..127
        const int bb = blk;               // 0..63
        const int j  = L & 63;
        const int gc = (L < GG_) ? L : (GG_ - 1);
        const bool isg = (gc >= 62 && gc < 93);
        const bool selhi = (j >= 32);
        const int sidx = selhi ? (j - 32) : j;
        float (*gA)[128] = (float(*)[128])smem;          // [2][128]
        float (*g2)[128] = (float(*)[128])(smem + 256);  // [2][128]

#define WLOAD(k) float w1_##k  = Whh1[gc * 31 + k]; \
                 float wi2_##k = Wih2[gc * 31 + k]; \
                 float wh2_##k = Whh2[gc * 31 + k];
        REP31(WLOAD)
#undef WLOAD
#define WPIN(k) asm("" : "+v"(w1_##k), "+v"(wi2_##k), "+v"(wh2_##k));
        REP31(WPIN)
#undef WPIN

        const float b2c = bih2[gc] + bhh2[gc];
        float hv = 0.0f, cv = 0.0f;

        float cur0 = pre1[(size_t)bb * 128 + L];
        float pnxt = pre1[((size_t)1 * 64 + bb) * 128 + L];
        float pnx2 = pre1[((size_t)2 * 64 + bb) * 128 + L];
        {
            float pa0 = cur0, pa1 = 0.0f;
#define DPE(k) { float hk = rdlane(hv, 32 + k); pa0 += w1_##k * hk; }
#define DPO(k) { float hk = rdlane(hv, 32 + k); pa1 += w1_##k * hk; }
            REP16E(DPE)
            REP15O(DPO)
#undef DPE
#undef DPO
            float a = pa0 + pa1;
            float z = isg ? (2.0f * a) : a;
            float s = 1.0f / (1.0f + __expf(-z));
            gA[1][L] = isg ? (2.0f * s - 1.0f) : s;
        }
        __syncthreads();
        {
            const float* gsrc = &gA[1][0];
            float ig = gsrc[sidx];
            float fg = gsrc[sidx + 31];
            float gg = gsrc[sidx + 62];
            float og = gsrc[sidx + 93];
            float cvn = fg * cv + ig * gg;
            float e = __expf(-2.0f * cvn);
            float hvn = og * (2.0f / (1.0f + e) - 1.0f);
            cv = selhi ? cvn : 0.0f;
            hv = selhi ? hvn : 0.0f;
        }

        for (int t = 0; t < TT_ - 1; t++) {
            const int pb = t & 1;
            const float cur = pnxt;
            pnxt = pnx2;
            if (t + 3 < TT_) pnx2 = pre1[((size_t)(t + 3) * 64 + bb) * 128 + L];

            float bi0 = b2c, bi1 = 0.0f, bh0 = 0.0f, bh1 = 0.0f;
            float pa0 = cur, pa1 = 0.0f;
#define DME(k) { float h1k = rdlane(hv, 32 + k); float h2k = rdlane(hv, k); \
                 bi0 += wi2_##k * h1k; bh0 += wh2_##k * h2k; pa0 += w1_##k * h1k; }
#define DMO(k) { float h1k = rdlane(hv, 32 + k); float h2k = rdlane(hv, k); \
                 bi1 += wi2_##k * h1k; bh1 += wh2_##k * h2k; pa1 += w1_##k * h1k; }
            REP16E(DME)
            REP15O(DMO)
#undef DME
#undef DMO
            float b = (bi0 + bi1) + (bh0 + bh1);
            float a = pa0 + pa1;
            {
                float z = isg ? (2.0f * b) : b;
                float s = 1.0f / (1.0f + __expf(-z));
                g2[pb][L] = isg ? (2.0f * s - 1.0f) : s;
            }
            {
                float z = isg ? (2.0f * a) : a;
                float s = 1.0f / (1.0f + __expf(-z));
                gA[pb][L] = isg ? (2.0f * s - 1.0f) : s;
            }
            __syncthreads();
            {
                const float* gsrc = selhi ? &gA[pb][0] : &g2[pb][0];
                float ig = gsrc[sidx];
                float fg = gsrc[sidx + 31];
                float gg = gsrc[sidx + 62];
                float og = gsrc[sidx + 93];
                cv = fg * cv + ig * gg;
                float e = __expf(-2.0f * cv);
                hv = og * (2.0f / (1.0f + e) - 1.0f);
            }
            if (L < HH_) h2a[((size_t)t * 64 + bb) * 32 + L] = hv;
            // progress publication at 64-step group boundary (t=63..447 -> g=0..6).
            // Release-add after wave-0's h2a stores; vmcnt drain + L2 writeback
            // make the group visible to consumer XCDs (validated in R11).
            if (((t & 63) == 63) && L == 0) aadd_rel(&flg[t >> 6], 1);
        }

        // tail: L2(511)
        {
            float bi0 = b2c, bi1 = 0.0f, bh0 = 0.0f, bh1 = 0.0f;
#define DTE(k) { float h1k = rdlane(hv, 32 + k); float h2k = rdlane(hv, k); \
                 bi0 += wi2_##k * h1k; bh0 += wh2_##k * h2k; }
#define DTO(k) { float h1k = rdlane(hv, 32 + k); float h2k = rdlane(hv, k); \
                 bi1 += wi2_##k * h1k; bh1 += wh2_##k * h2k; }
            REP16E(DTE)
            REP15O(DTO)
#undef DTE
#undef DTO
            float b = (bi0 + bi1) + (bh0 + bh1);
            float z = isg ? (2.0f * b) : b;
            float s = 1.0f / (1.0f + __expf(-z));
            g2[1][L] = isg ? (2.0f * s - 1.0f) : s;
        }
        __syncthreads();
        {
            const float* gsrc = &g2[1][0];
            float ig = gsrc[sidx];
            float fg = gsrc[sidx + 31];
            float gg = gsrc[sidx + 62];
            float og = gsrc[sidx + 93];
            float cvn = fg * cv + ig * gg;
            float e = __expf(-2.0f * cvn);
            float hvn = og * (2.0f / (1.0f + e) - 1.0f);
            cv = selhi ? cv : cvn;
            hv = selhi ? hv : hvn;
        }
        if (L < HH_) h2a[((size_t)(TT_ - 1) * 64 + bb) * 32 + L] = hv;
        if (L == 0) aadd_rel(&flg[7], 1);   // group 7 (t=448..511) complete

        // future
#define MLOAD(k) float m_##k = Mv[gc * 32 + k];
        REP31(MLOAD)
#undef MLOAD
        float m_31 = Mv[gc * 32 + 31];
#define MPIN(k) asm("" : "+v"(m_##k));
        REP31(MPIN)
#undef MPIN
        asm("" : "+v"(m_31));
        const float b1c = bih1[gc] + bhh1[gc];

        for (int sft = 0; sft < FUT_; sft++) {
            float pa0 = b1c + m_31, pa1 = 0.0f;
#define DFE(k) { float h2k = rdlane(hv, k); pa0 += m_##k * h2k; }
#define DFO(k) { float h2k = rdlane(hv, k); pa1 += m_##k * h2k; }
            REP16E(DFE)
            REP15O(DFO)
#undef DFE
#undef DFO
#define DGE(k) { float h1k = rdlane(hv, 32 + k); pa0 += w1_##k * h1k; }
#define DGO(k) { float h1k = rdlane(hv, 32 + k); pa1 += w1_##k * h1k; }
            REP16E(DGE)
            REP15O(DGO)
#undef DGE
#undef DGO
            {
                float a = pa0 + pa1;
                float z = isg ? (2.0f * a) : a;
                float s = 1.0f / (1.0f + __expf(-z));
                gA[0][L] = isg ? (2.0f * s - 1.0f) : s;
            }
            __syncthreads();
            {
                const float* gsrc = &gA[0][0];
                float ig = gsrc[sidx];
                float fg = gsrc[sidx + 31];
                float gg = gsrc[sidx + 62];
                float og = gsrc[sidx + 93];
                float cvn = fg * cv + ig * gg;
                float e = __expf(-2.0f * cvn);
                float hvn = og * (2.0f / (1.0f + e) - 1.0f);
                cv = selhi ? cvn : cv;
                hv = selhi ? hvn : hv;
            }
            float bi0 = b2c, bi1 = 0.0f, bh0 = 0.0f, bh1 = 0.0f;
#define DHE(k) { float h1k = rdlane(hv, 32 + k); float h2k = rdlane(hv, k); \
                 bi0 += wi2_##k * h1k; bh0 += wh2_##k * h2k; }
#define DHO(k) { float h1k = rdlane(hv, 32 + k); float h2k = rdlane(hv, k); \
                 bi1 += wi2_##k * h1k; bh1 += wh2_##k * h2k; }
            REP16E(DHE)
            REP15O(DHO)
#undef DHE
#undef DHO
            {
                float b = (bi0 + bi1) + (bh0 + bh1);
                float z = isg ? (2.0f * b) : b;
                float s = 1.0f / (1.0f + __expf(-z));
                g2[0][L] = isg ? (2.0f * s - 1.0f) : s;
            }
            __syncthreads();
            {
                const float* gsrc = &g2[0][0];
                float ig = gsrc[sidx];
                float fg = gsrc[sidx + 31];
                float gg = gsrc[sidx + 62];
                float og = gsrc[sidx + 93];
                float cvn = fg * cv + ig * gg;
                float e = __expf(-2.0f * cvn);
                float hvn = og * (2.0f / (1.0f + e) - 1.0f);
                cv = selhi ? cv : cvn;
                hv = selhi ? hv : hvn;
            }
            if (L < HH_) h2a[((size_t)(TT_ + sft) * 64 + bb) * 32 + L] = hv;
        }
        if (L == 0) aadd_rel(&flg[8], 1);   // future group complete
    }
}

extern "C" void kernel_launch(void* const* d_in, const int* in_sizes, int n_in,
                              void* d_out, int out_size, void* d_ws, size_t ws_size,
                              hipStream_t stream) {
    (void)in_sizes; (void)n_in; (void)out_size; (void)ws_size;
    const float* X    = (const float*)d_in[0];
    const float* Wih1 = (const float*)d_in[1];
    const float* Whh1 = (const float*)d_in[2];
    const float* bih1 = (const float*)d_in[3];
    const float* bhh1 = (const float*)d_in[4];
    const float* Wih2 = (const float*)d_in[5];
    const float* Whh2 = (const float*)d_in[6];
    const float* bih2 = (const float*)d_in[7];
    const float* bhh2 = (const float*)d_in[8];
    const float* Wlin = (const float*)d_in[9];
    const float* blin = (const float*)d_in[10];
    // d_in[11] = future = 16 (constant for this problem)

    float* ws   = (float*)d_ws;
    float* pre1 = ws + PRE1_OFF;
    float* h2a  = ws + H2A_OFF;
    float* WT   = ws + WT_OFF;
    float* Mv   = ws + MV_OFF;
    int*   flg  = (int*)(ws + FLG_OFF);
    float* out  = (float*)d_out;

    hipLaunchKernelGGL(k_zero,  dim3(1),   dim3(64),  0, stream, flg);
    hipLaunchKernelGGL(k_front, dim3(396), dim3(256), 0, stream,
                       X, Wih1, bih1, bhh1, Wlin, blin, pre1, WT, Mv);
    hipLaunchKernelGGL(k_23, dim3(KBLK + NCONS), dim3(256), 0, stream,
                       pre1, Whh1, Wih2, Whh2, bih1, bhh1, bih2, bhh2,
                       Mv, WT, blin, h2a, out, flg);
}